// Round 13
// baseline (449.916 us; speedup 1.0000x reference)
//
#include <hip/hip_runtime.h>

#define N_NODES  100000
#define N_EDGES  3200000
#define NFEAT    256
#define NHID     128
#define NCLASS   16
#define TEXT_CNT 50000

#define RPB      256                          // rows per bucket
#define NB       ((N_NODES + RPB - 1) / RPB)  // 391 buckets
#define CAP      16384                        // fixed bucket capacity (2^14)
#define SC_EDGES 8192                         // edges per scatter block
#define SC_BLKS  ((N_EDGES + SC_EDGES - 1) / SC_EDGES)  // 391
#define FN_CAPL  9216                         // finalize LDS edge capacity (mean+11sigma)
#define COLHALF  (N_NODES / 2)

typedef unsigned int uint;
typedef __bf16 bf16x8 __attribute__((ext_vector_type(8)));
typedef __bf16 bf16x4 __attribute__((ext_vector_type(4)));
typedef float f32x4 __attribute__((ext_vector_type(4)));

__device__ inline uint bf16_rne(float f) {
  uint u = __float_as_uint(f);
  return (u + 0x7fffu + ((u >> 16) & 1u)) >> 16;
}
__device__ inline float bf_lo(uint u) { return __uint_as_float(u << 16); }
__device__ inline float bf_hi(uint u) { return __uint_as_float(u & 0xffff0000u); }

// ---------------- fused prep: W1t, W2t, Wc1/2, bc1/2, cursor init ----------------

__global__ __launch_bounds__(256) void prep_kernel(const float* __restrict__ W1,
                                                   const float* __restrict__ W2,
                                                   const float* __restrict__ b2,
                                                   const float* __restrict__ cW1,
                                                   const float* __restrict__ cb1,
                                                   const float* __restrict__ cW2,
                                                   const float* __restrict__ cb2,
                                                   unsigned short* __restrict__ W1t,
                                                   unsigned short* __restrict__ W2t,
                                                   float* __restrict__ Wc1, float* __restrict__ bc1,
                                                   float* __restrict__ Wc2, float* __restrict__ bc2,
                                                   int* __restrict__ gcursor) {
  int idx = blockIdx.x * 256 + threadIdx.x;
  if (idx < 32768) {                       // W1t[n][k] = bf16(W1[k][n]), K=256,N=128
    int n = idx >> 8, k = idx & 255;
    W1t[idx] = (unsigned short)bf16_rne(W1[(size_t)k * NHID + n]);
  } else if (idx < 65536) {                // W2t[n][k] = bf16(W2[k][n]), K=128,N=256
    int i2 = idx - 32768;
    int n = i2 >> 7, k = i2 & 127;
    W2t[i2] = (unsigned short)bf16_rne(W2[(size_t)k * NFEAT + n]);
  } else if (idx < 69632) {                // Wc = W2 @ cW
    int e = idx - 65536;
    int set = e >> 11;
    int e2 = e & 2047;
    int i = e2 >> 4, c = e2 & 15;
    const float* cw = set ? cW2 : cW1;
    float acc = 0.f;
    for (int k = 0; k < NFEAT; ++k)
      acc += W2[(size_t)i * NFEAT + k] * cw[k * NCLASS + c];
    (set ? Wc2 : Wc1)[e2] = acc;
    if (e < 32) {
      int s2 = e >> 4, c2 = e & 15;
      const float* cwb = s2 ? cW2 : cW1;
      float b = (s2 ? cb2 : cb1)[c2];
      for (int k = 0; k < NFEAT; ++k) b += b2[k] * cwb[k * NCLASS + c2];
      (s2 ? bc2 : bc1)[c2] = b;
    }
  } else if (idx < 69632 + NB) {           // gcursor[b] = b*CAP
    int b = idx - 69632;
    gcursor[b] = b * CAP;
  }
}

// ---------------- scatter with in-LDS counting sort ----------------
// packedA[p] = { (rowlocal<<17) | col , float_bits(val) }

__global__ __launch_bounds__(512) void scatter_sort_kernel(const int* __restrict__ rows,
                                                           const int* __restrict__ cols,
                                                           const float* __restrict__ vals,
                                                           int* __restrict__ gcursor,
                                                           int2* __restrict__ packedA, int E) {
  __shared__ int2 eds[SC_EDGES];   // 64 KB
  __shared__ int hist[512];        // counts -> inclusive prefix
  __shared__ int bcnt[NB];
  __shared__ int lofs[NB];
  __shared__ int lcur[NB];
  __shared__ int gofs[NB];
  int t = threadIdx.x;
  int base = blockIdx.x * SC_EDGES;
  hist[t] = 0;
  __syncthreads();
#pragma unroll
  for (int i = 0; i < SC_EDGES / 512; ++i) {
    int e = base + i * 512 + t;
    if (e < E) atomicAdd(&hist[rows[e] >> 8], 1);
  }
  __syncthreads();
  int v = hist[t];
  if (t < NB) bcnt[t] = v;
  __syncthreads();
  for (int off = 1; off < 512; off <<= 1) {
    int u = (t >= off) ? hist[t - off] : 0;
    __syncthreads();
    hist[t] += u;
    __syncthreads();
  }
  if (t < NB) {
    int ex = hist[t] - v;
    lofs[t] = ex;
    lcur[t] = ex;
    gofs[t] = v ? atomicAdd(&gcursor[t], v) : 0;
  }
  __syncthreads();
#pragma unroll
  for (int i = 0; i < SC_EDGES / 512; ++i) {
    int e = base + i * 512 + t;
    if (e < E) {
      int r = rows[e];
      int b = r >> 8;
      int p = atomicAdd(&lcur[b], 1);
      eds[p] = make_int2(((r & 255) << 17) | cols[e], __float_as_int(vals[e]));
    }
  }
  __syncthreads();
  int wid = t >> 6, lane = t & 63;
  for (int b = wid; b < NB; b += 8) {
    int cnt = bcnt[b];
    int lo = lofs[b];
    int go = gofs[b];
    int lim = (b + 1) << 14;
    for (int j = lane; j < cnt; j += 64)
      if (go + j < lim) packedA[go + j] = eds[lo + j];
  }
}

// ---------------- per-bucket CSR finalize: in-LDS (row, colhalf) sort, coalesced write ----------------
// key = (rowlocal<<1) | (col >= COLHALF)  -> 512 bins
// packedB[p] = { col<<8 (byte offset of feature row), float_bits(val) }

__global__ __launch_bounds__(512) void csr_finalize_kernel(const int* __restrict__ gcursor,
                                                           const int2* __restrict__ packedA,
                                                           int2* __restrict__ packedB,
                                                           int* __restrict__ row_ptr) {
  __shared__ int2 eds[FN_CAPL];    // 72 KB
  __shared__ int pre[512];
  __shared__ int kh[512];
  __shared__ int kofs[512];
  __shared__ int kcur[512];
  int b = blockIdx.x;
  int t = threadIdx.x;
  int cntt = (t < NB) ? (gcursor[t] - t * CAP) : 0;
  pre[t] = cntt;
  __syncthreads();
  for (int off = 1; off < 512; off <<= 1) {
    int u = (t >= off) ? pre[t - off] : 0;
    __syncthreads();
    pre[t] += u;
    __syncthreads();
  }
  int cnt = gcursor[b] - b * CAP;
  int gout = pre[b] - cnt;     // exclusive prefix
  int s0 = b * CAP;
  int end = s0 + cnt;
  kh[t] = 0;
  __syncthreads();
  for (int i = s0 + t; i < end; i += 512) {
    int2 pk = packedA[i];
    int key = ((pk.x >> 17) << 1) | ((pk.x & 0x1FFFF) >= COLHALF);
    atomicAdd(&kh[key], 1);
  }
  __syncthreads();
  int v = kh[t];
  kofs[t] = v;
  __syncthreads();
  for (int off = 1; off < 512; off <<= 1) {
    int u = (t >= off) ? kofs[t - off] : 0;
    __syncthreads();
    kofs[t] += u;
    __syncthreads();
  }
  kcur[t] = kofs[t] - v;     // exclusive per-key offset within bucket
  __syncthreads();
  if (t < RPB) {
    int row = b * RPB + t;
    if (row < N_NODES) row_ptr[row] = gout + kcur[2 * t];
  }
  if (b == 0 && t == 0) row_ptr[N_NODES] = N_EDGES;
  __syncthreads();
  if (cnt <= FN_CAPL) {
    for (int i = s0 + t; i < end; i += 512) {
      int2 pk = packedA[i];
      int key = ((pk.x >> 17) << 1) | ((pk.x & 0x1FFFF) >= COLHALF);
      int p = atomicAdd(&kcur[key], 1);
      eds[p] = pk;
    }
    __syncthreads();
    for (int i = t; i < cnt; i += 512) {
      int2 pk = eds[i];
      packedB[gout + i] = make_int2((pk.x & 0x1FFFF) << 8, pk.y);
    }
  } else {
    for (int i = s0 + t; i < end; i += 512) {
      int2 pk = packedA[i];
      int key = ((pk.x >> 17) << 1) | ((pk.x & 0x1FFFF) >= COLHALF);
      int p = atomicAdd(&kcur[key], 1);
      packedB[gout + p] = make_int2((pk.x & 0x1FFFF) << 8, pk.y);
    }
  }
}

// ---------------- bf16 MFMA GEMM body: C[M,N] = A[M,K] @ Bt^T (+bias) ----------------

template <int A_FP32, int OUT_BF16, int K, int N>
__device__ __forceinline__ void gemm_body(int bx, int by, const void* __restrict__ Aptr,
                                          const __bf16* __restrict__ Bt,
                                          const float* __restrict__ bias,
                                          void* __restrict__ Cptr, int M,
                                          __bf16* __restrict__ As, __bf16* __restrict__ Bs) {
  int tid = threadIdx.x;
  int lane = tid & 63;
  int w = tid >> 6;
  int wr = w >> 1, wc = w & 1;
  int brow = bx * 128;
  int bcol = by * 128;
  int r16 = lane & 15, kb = lane >> 4;

  f32x4 acc[4][4];
#pragma unroll
  for (int m = 0; m < 4; ++m)
#pragma unroll
    for (int n = 0; n < 4; ++n) acc[m][n] = (f32x4){0.f, 0.f, 0.f, 0.f};

  for (int k0 = 0; k0 < K; k0 += 32) {
    if (A_FP32) {
      const float* A = (const float*)Aptr;
#pragma unroll
      for (int i = 0; i < 4; ++i) {
        int idx = tid + i * 256;
        int row = idx >> 3;
        int kq = (idx & 7) << 2;
        int gr = brow + row;
        float4 v = make_float4(0.f, 0.f, 0.f, 0.f);
        if (gr < M) v = *(const float4*)&A[(size_t)gr * K + k0 + kq];
        bf16x4 o;
        o[0] = (__bf16)v.x; o[1] = (__bf16)v.y; o[2] = (__bf16)v.z; o[3] = (__bf16)v.w;
        *(bf16x4*)&As[row * 40 + kq] = o;
      }
    } else {
      const __bf16* A = (const __bf16*)Aptr;
#pragma unroll
      for (int i = 0; i < 2; ++i) {
        int idx = tid + i * 256;
        int row = idx >> 2;
        int kq = (idx & 3) << 3;
        int gr = brow + row;
        bf16x8 v = {};
        if (gr < M) v = *(const bf16x8*)&A[(size_t)gr * K + k0 + kq];
        *(bf16x8*)&As[row * 40 + kq] = v;
      }
    }
#pragma unroll
    for (int i = 0; i < 2; ++i) {
      int idx = tid + i * 256;
      int col = idx >> 2;
      int kq = (idx & 3) << 3;
      bf16x8 v = *(const bf16x8*)&Bt[(size_t)(bcol + col) * K + k0 + kq];
      *(bf16x8*)&Bs[col * 40 + kq] = v;
    }
    __syncthreads();

    bf16x8 a[4], b[4];
#pragma unroll
    for (int m = 0; m < 4; ++m)
      a[m] = *(bf16x8*)&As[(wr * 64 + m * 16 + r16) * 40 + kb * 8];
#pragma unroll
    for (int n = 0; n < 4; ++n)
      b[n] = *(bf16x8*)&Bs[(wc * 64 + n * 16 + r16) * 40 + kb * 8];
#pragma unroll
    for (int m = 0; m < 4; ++m)
#pragma unroll
      for (int n = 0; n < 4; ++n)
        acc[m][n] = __builtin_amdgcn_mfma_f32_16x16x32_bf16(a[m], b[n], acc[m][n], 0, 0, 0);
    __syncthreads();
  }

  int crow0 = brow + wr * 64;
  int ccol0 = bcol + wc * 64;
#pragma unroll
  for (int n = 0; n < 4; ++n) {
    int col = ccol0 + n * 16 + r16;
    float bv = bias ? bias[col] : 0.f;
#pragma unroll
    for (int m = 0; m < 4; ++m) {
#pragma unroll
      for (int r = 0; r < 4; ++r) {
        int row = crow0 + m * 16 + kb * 4 + r;
        if (row < M) {
          float val = acc[m][n][r] + bv;
          if (OUT_BF16)
            ((unsigned short*)Cptr)[(size_t)row * N + col] = (unsigned short)bf16_rne(val);
          else
            ((float*)Cptr)[(size_t)row * N + col] = val;
        }
      }
    }
  }
}

// ---------------- standalone GEMM kernel (gemm1) ----------------

template <int A_FP32, int OUT_BF16, int K, int N>
__global__ __launch_bounds__(256) void gemm_mfma_kernel(const void* __restrict__ Aptr,
                                                        const __bf16* __restrict__ Bt,
                                                        const float* __restrict__ bias,
                                                        void* __restrict__ Cptr, int M) {
  __shared__ __align__(16) __bf16 smem[2 * 128 * 40];
  gemm_body<A_FP32, OUT_BF16, K, N>(blockIdx.x, blockIdx.y, Aptr, Bt, bias, Cptr, M,
                                    smem, smem + 128 * 40);
}

// ---------------- CSR SpMM over a FEATURE-HALF (64 features = 128 B/row) ----------------
// Lane layout: q = lane>>4 (edge slot 0..3), l16 = lane&15 (16 x 8B = 128 B).
// Pass h gathers only bytes [128h, 128h+128) of each source row -> 12.8 MB working set.

#define FMAG(U, V)                                                   \
  a0 += (V) * bf_lo((U).x); a1 += (V) * bf_hi((U).x);                \
  a2 += (V) * bf_lo((U).y); a3 += (V) * bf_hi((U).y);

__global__ __launch_bounds__(256) void spmm_half_kernel(const int* __restrict__ row_ptr,
                                                        const int2* __restrict__ packed,
                                                        const uint* __restrict__ src,   // [n][64] dwords
                                                        uint* __restrict__ dst,         // [n][64] dwords
                                                        const float* __restrict__ bias,
                                                        int relu, int nrows, int h) {
  int tid = threadIdx.x;
  int lane = tid & 63;
  int q = lane >> 4;
  int l16 = lane & 15;
  int row = blockIdx.x * 4 + (tid >> 6);
  if (row >= nrows) return;
  int s = row_ptr[row];
  int e = row_ptr[row + 1];
  const char* srcb = (const char*)src + (h << 7) + (l16 << 3);
  float a0 = 0.f, a1 = 0.f, a2 = 0.f, a3 = 0.f;
  int i = s;
  // 32 edges per iter: 8 gather instructions in flight
  for (; i + 32 <= e; i += 32) {
    int2 m0 = packed[i + 0 + q],  m1 = packed[i + 4 + q];
    int2 m2 = packed[i + 8 + q],  m3 = packed[i + 12 + q];
    int2 m4 = packed[i + 16 + q], m5 = packed[i + 20 + q];
    int2 m6 = packed[i + 24 + q], m7 = packed[i + 28 + q];
    uint2 u0 = *(const uint2*)(srcb + (uint)m0.x);
    uint2 u1 = *(const uint2*)(srcb + (uint)m1.x);
    uint2 u2 = *(const uint2*)(srcb + (uint)m2.x);
    uint2 u3 = *(const uint2*)(srcb + (uint)m3.x);
    uint2 u4 = *(const uint2*)(srcb + (uint)m4.x);
    uint2 u5 = *(const uint2*)(srcb + (uint)m5.x);
    uint2 u6 = *(const uint2*)(srcb + (uint)m6.x);
    uint2 u7 = *(const uint2*)(srcb + (uint)m7.x);
    float v0 = __int_as_float(m0.y), v1 = __int_as_float(m1.y);
    float v2 = __int_as_float(m2.y), v3 = __int_as_float(m3.y);
    float v4 = __int_as_float(m4.y), v5 = __int_as_float(m5.y);
    float v6 = __int_as_float(m6.y), v7 = __int_as_float(m7.y);
    FMAG(u0, v0) FMAG(u1, v1) FMAG(u2, v2) FMAG(u3, v3)
    FMAG(u4, v4) FMAG(u5, v5) FMAG(u6, v6) FMAG(u7, v7)
  }
  for (; i + 16 <= e; i += 16) {
    int2 m0 = packed[i + 0 + q], m1 = packed[i + 4 + q];
    int2 m2 = packed[i + 8 + q], m3 = packed[i + 12 + q];
    uint2 u0 = *(const uint2*)(srcb + (uint)m0.x);
    uint2 u1 = *(const uint2*)(srcb + (uint)m1.x);
    uint2 u2 = *(const uint2*)(srcb + (uint)m2.x);
    uint2 u3 = *(const uint2*)(srcb + (uint)m3.x);
    float v0 = __int_as_float(m0.y), v1 = __int_as_float(m1.y);
    float v2 = __int_as_float(m2.y), v3 = __int_as_float(m3.y);
    FMAG(u0, v0) FMAG(u1, v1) FMAG(u2, v2) FMAG(u3, v3)
  }
  for (; i + 8 <= e; i += 8) {
    int2 m0 = packed[i + 0 + q], m1 = packed[i + 4 + q];
    uint2 u0 = *(const uint2*)(srcb + (uint)m0.x);
    uint2 u1 = *(const uint2*)(srcb + (uint)m1.x);
    float v0 = __int_as_float(m0.y), v1 = __int_as_float(m1.y);
    FMAG(u0, v0) FMAG(u1, v1)
  }
  for (; i < e; i += 4) {
    int ee = i + q;
    int ok = ee < e;
    int2 m = packed[ok ? ee : (e - 1)];
    uint2 u = *(const uint2*)(srcb + (uint)m.x);
    float v = ok ? __int_as_float(m.y) : 0.f;
    FMAG(u, v)
  }
  // reduce across the 4 edge slots (lanes differing in bits 4,5)
  a0 += __shfl_xor(a0, 16); a1 += __shfl_xor(a1, 16);
  a2 += __shfl_xor(a2, 16); a3 += __shfl_xor(a3, 16);
  a0 += __shfl_xor(a0, 32); a1 += __shfl_xor(a1, 32);
  a2 += __shfl_xor(a2, 32); a3 += __shfl_xor(a3, 32);
  if (q == 0) {
    if (bias) {
      int f0 = (h << 6) + (l16 << 2);
      a0 += bias[f0 + 0]; a1 += bias[f0 + 1];
      a2 += bias[f0 + 2]; a3 += bias[f0 + 3];
    }
    if (relu) {
      a0 = fmaxf(a0, 0.f); a1 = fmaxf(a1, 0.f);
      a2 = fmaxf(a2, 0.f); a3 = fmaxf(a3, 0.f);
    }
    uint2 o;
    o.x = bf16_rne(a0) | (bf16_rne(a1) << 16);
    o.y = bf16_rne(a2) | (bf16_rne(a3) << 16);
    *(uint2*)&dst[(size_t)row * 64 + (h << 5) + (l16 << 1)] = o;
  }
}

// ---------------- classifier body ----------------

__device__ __forceinline__ void cls_body(int bid, int clsblks,
                                         const uint* __restrict__ t3,
                                         const float* __restrict__ Wc1,
                                         const float* __restrict__ bc1,
                                         const float* __restrict__ Wc2,
                                         const float* __restrict__ bc2,
                                         float* __restrict__ out1,
                                         float* __restrict__ out2) {
  int half = clsblks >> 1;
  int region = bid >= half;
  int b = region ? bid - half : bid;
  const float* Wc = region ? Wc2 : Wc1;
  const float* bc = region ? bc2 : bc1;
  float* outp = region ? out2 : out1;
  int row0 = region ? TEXT_CNT : 0;
  int nrows = region ? (N_NODES - TEXT_CNT) : TEXT_CNT;

  int lane = threadIdx.x & 63;
  int wav = b * 4 + (threadIdx.x >> 6);
  int nw = half * 4;
  int c = lane & 15;
  int kg = lane >> 4;
  float w[32];
#pragma unroll
  for (int j = 0; j < 32; ++j) w[j] = Wc[(kg * 32 + j) * NCLASS + c];
  float bcv = bc[c];
  for (int r = wav; r < nrows; r += nw) {
    const uint4* rp = (const uint4*)&t3[(size_t)(row0 + r) * 64 + kg * 16];
    float acc = 0.f;
#pragma unroll
    for (int qq = 0; qq < 4; ++qq) {
      uint4 u = rp[qq];
      acc += bf_lo(u.x) * w[qq * 8 + 0] + bf_hi(u.x) * w[qq * 8 + 1]
           + bf_lo(u.y) * w[qq * 8 + 2] + bf_hi(u.y) * w[qq * 8 + 3]
           + bf_lo(u.z) * w[qq * 8 + 4] + bf_hi(u.z) * w[qq * 8 + 5]
           + bf_lo(u.w) * w[qq * 8 + 6] + bf_hi(u.w) * w[qq * 8 + 7];
    }
    acc += __shfl_xor(acc, 16);
    acc += __shfl_xor(acc, 32);
    if (lane < 16) outp[(size_t)r * NCLASS + lane] = acc + bcv;
  }
}

// ---------------- fused: gemm2 (blocks [0,g2blks)) + classifiers ----------------

__global__ __launch_bounds__(256) void fused_g2c_kernel(const uint* __restrict__ t3u,
                                                        const __bf16* __restrict__ W2t,
                                                        const float* __restrict__ b2,
                                                        float* __restrict__ outp,
                                                        const float* __restrict__ Wc1,
                                                        const float* __restrict__ bc1,
                                                        const float* __restrict__ Wc2,
                                                        const float* __restrict__ bc2,
                                                        float* __restrict__ out1,
                                                        float* __restrict__ out2,
                                                        int g2blks, int clsblks) {
  __shared__ __align__(16) __bf16 smem[2 * 128 * 40];
  if ((int)blockIdx.x < g2blks) {
    int bx = blockIdx.x >> 1;
    int by = blockIdx.x & 1;
    gemm_body<0, 0, NHID, NFEAT>(bx, by, t3u, W2t, b2, outp, N_NODES,
                                 smem, smem + 128 * 40);
  } else {
    cls_body(blockIdx.x - g2blks, clsblks, t3u, Wc1, bc1, Wc2, bc2, out1, out2);
  }
}

// ---------------- launch ----------------

extern "C" void kernel_launch(void* const* d_in, const int* in_sizes, int n_in,
                              void* d_out, int out_size, void* d_ws, size_t ws_size,
                              hipStream_t stream) {
  const float* x     = (const float*)d_in[0];
  const int*   arows = (const int*)d_in[1];
  const int*   acols = (const int*)d_in[2];
  const float* avals = (const float*)d_in[3];
  const float* W1    = (const float*)d_in[4];
  const float* b1    = (const float*)d_in[5];
  const float* W2    = (const float*)d_in[6];
  const float* b2    = (const float*)d_in[7];
  const float* cW1   = (const float*)d_in[8];
  const float* cb1   = (const float*)d_in[9];
  const float* cW2   = (const float*)d_in[10];
  const float* cb2   = (const float*)d_in[11];
  float* outp = (float*)d_out;

  char* ws = (char*)d_ws;
  size_t off = 0;
  auto alloc = [&](size_t bytes) -> void* {
    void* p = ws + off;
    off += (bytes + 255) & ~(size_t)255;
    return p;
  };
  uint*  t1u     = (uint*) alloc((size_t)N_NODES * 64 * 4);   // bf16 [N][128]
  uint*  hu      = (uint*) alloc((size_t)N_NODES * 64 * 4);   // bf16 [N][128]
  uint*  t3u     = (uint*) alloc((size_t)N_NODES * 64 * 4);   // bf16 [N][128]
  int2*  packedA = (int2*) alloc((size_t)NB * CAP * 8);       // fixed-cap buckets
  int2*  packedB = (int2*) alloc((size_t)N_EDGES * 8);        // row-grouped (CSR)
  int*   gcursor = (int*)  alloc((size_t)NB * 4);
  int*   rowp    = (int*)  alloc((size_t)(N_NODES + 1) * 4);
  unsigned short* W1t = (unsigned short*)alloc((size_t)NHID * NFEAT * 2);  // [128][256]
  unsigned short* W2t = (unsigned short*)alloc((size_t)NFEAT * NHID * 2);  // [256][128]
  float* Wc1     = (float*)alloc(NHID * NCLASS * 4);
  float* Wc2     = (float*)alloc(NHID * NCLASS * 4);
  float* bc1     = (float*)alloc(64);
  float* bc2     = (float*)alloc(64);

  // ---- 1. fused prep (weights + cursors) ----
  prep_kernel<<<(69632 + NB + 255) / 256, 256, 0, stream>>>(
      W1, W2, b2, cW1, cb1, cW2, cb2, W1t, W2t, Wc1, bc1, Wc2, bc2, gcursor);

  // ---- 2. scatter with in-LDS counting sort ----
  scatter_sort_kernel<<<SC_BLKS, 512, 0, stream>>>(arows, acols, avals, gcursor, packedA, N_EDGES);

  // ---- 3. finalize: in-LDS (row,colhalf) sort, coalesced CSR write ----
  csr_finalize_kernel<<<NB, 512, 0, stream>>>(gcursor, packedA, packedB, rowp);

  // ---- 4. t1 = bf16(x @ W1) ----
  int mblk = (N_NODES + 127) / 128;  // 782
  gemm_mfma_kernel<1, 1, NFEAT, NHID><<<dim3(mblk, 1), 256, 0, stream>>>(
      x, (const __bf16*)W1t, nullptr, t1u, N_NODES);

  // ---- 5. h = bf16(relu(A @ t1 + b1)) : two feature-half passes ----
  int sblk = (N_NODES + 3) / 4;
  spmm_half_kernel<<<sblk, 256, 0, stream>>>(rowp, packedB, t1u, hu, b1, 1, N_NODES, 0);
  spmm_half_kernel<<<sblk, 256, 0, stream>>>(rowp, packedB, t1u, hu, b1, 1, N_NODES, 1);
  // ---- 6. t3 = bf16(A @ h) : two feature-half passes ----
  spmm_half_kernel<<<sblk, 256, 0, stream>>>(rowp, packedB, hu, t3u, nullptr, 0, N_NODES, 0);
  spmm_half_kernel<<<sblk, 256, 0, stream>>>(rowp, packedB, hu, t3u, nullptr, 0, N_NODES, 1);

  // ---- 7. fused: out = t3 @ W2 + b2 (fp32) + classifiers ----
  int g2blks = mblk * 2;   // 1564
  int clsblks = 2048;
  fused_g2c_kernel<<<g2blks + clsblks, 256, 0, stream>>>(
      t3u, (const __bf16*)W2t, b2, outp, Wc1, bc1, Wc2, bc2,
      outp + (size_t)N_NODES * NFEAT,
      outp + (size_t)N_NODES * NFEAT + (size_t)TEXT_CNT * NCLASS,
      g2blks, clsblks);
}

// Round 14
// 404.412 us; speedup vs baseline: 1.1125x; 1.1125x over previous
//
#include <hip/hip_runtime.h>

#define N_NODES  100000
#define N_EDGES  3200000
#define NFEAT    256
#define NHID     128
#define NCLASS   16
#define TEXT_CNT 50000

#define RPB      256                          // rows per bucket
#define NB       ((N_NODES + RPB - 1) / RPB)  // 391 buckets
#define CAP      16384                        // fixed bucket capacity (2^14)
#define SC_EDGES 8192                         // edges per scatter block
#define SC_BLKS  ((N_EDGES + SC_EDGES - 1) / SC_EDGES)  // 391
#define FN_CAPL  9216                         // finalize LDS edge capacity (mean+11sigma)
#define COLHALF  (N_NODES / 2)

typedef unsigned int uint;
typedef __bf16 bf16x8 __attribute__((ext_vector_type(8)));
typedef __bf16 bf16x4 __attribute__((ext_vector_type(4)));
typedef float f32x4 __attribute__((ext_vector_type(4)));

__device__ inline uint bf16_rne(float f) {
  uint u = __float_as_uint(f);
  return (u + 0x7fffu + ((u >> 16) & 1u)) >> 16;
}
__device__ inline float bf_lo(uint u) { return __uint_as_float(u << 16); }
__device__ inline float bf_hi(uint u) { return __uint_as_float(u & 0xffff0000u); }

// ---------------- fused prep: W1t, W2t, Wc1/2, bc1/2, cursor init ----------------

__global__ __launch_bounds__(256) void prep_kernel(const float* __restrict__ W1,
                                                   const float* __restrict__ W2,
                                                   const float* __restrict__ b2,
                                                   const float* __restrict__ cW1,
                                                   const float* __restrict__ cb1,
                                                   const float* __restrict__ cW2,
                                                   const float* __restrict__ cb2,
                                                   unsigned short* __restrict__ W1t,
                                                   unsigned short* __restrict__ W2t,
                                                   float* __restrict__ Wc1, float* __restrict__ bc1,
                                                   float* __restrict__ Wc2, float* __restrict__ bc2,
                                                   int* __restrict__ gcursor) {
  int idx = blockIdx.x * 256 + threadIdx.x;
  if (idx < 32768) {                       // W1t[n][k] = bf16(W1[k][n]), K=256,N=128
    int n = idx >> 8, k = idx & 255;
    W1t[idx] = (unsigned short)bf16_rne(W1[(size_t)k * NHID + n]);
  } else if (idx < 65536) {                // W2t[n][k] = bf16(W2[k][n]), K=128,N=256
    int i2 = idx - 32768;
    int n = i2 >> 7, k = i2 & 127;
    W2t[i2] = (unsigned short)bf16_rne(W2[(size_t)k * NFEAT + n]);
  } else if (idx < 69632) {                // Wc = W2 @ cW
    int e = idx - 65536;
    int set = e >> 11;
    int e2 = e & 2047;
    int i = e2 >> 4, c = e2 & 15;
    const float* cw = set ? cW2 : cW1;
    float acc = 0.f;
    for (int k = 0; k < NFEAT; ++k)
      acc += W2[(size_t)i * NFEAT + k] * cw[k * NCLASS + c];
    (set ? Wc2 : Wc1)[e2] = acc;
    if (e < 32) {
      int s2 = e >> 4, c2 = e & 15;
      const float* cwb = s2 ? cW2 : cW1;
      float b = (s2 ? cb2 : cb1)[c2];
      for (int k = 0; k < NFEAT; ++k) b += b2[k] * cwb[k * NCLASS + c2];
      (s2 ? bc2 : bc1)[c2] = b;
    }
  } else if (idx < 69632 + NB) {           // gcursor[b] = b*CAP
    int b = idx - 69632;
    gcursor[b] = b * CAP;
  }
}

// ---------------- scatter with in-LDS counting sort ----------------
// packedA[p] = { (rowlocal<<17) | col , float_bits(val) }

__global__ __launch_bounds__(512) void scatter_sort_kernel(const int* __restrict__ rows,
                                                           const int* __restrict__ cols,
                                                           const float* __restrict__ vals,
                                                           int* __restrict__ gcursor,
                                                           int2* __restrict__ packedA, int E) {
  __shared__ int2 eds[SC_EDGES];   // 64 KB
  __shared__ int hist[512];        // counts -> inclusive prefix
  __shared__ int bcnt[NB];
  __shared__ int lofs[NB];
  __shared__ int lcur[NB];
  __shared__ int gofs[NB];
  int t = threadIdx.x;
  int base = blockIdx.x * SC_EDGES;
  hist[t] = 0;
  __syncthreads();
#pragma unroll
  for (int i = 0; i < SC_EDGES / 512; ++i) {
    int e = base + i * 512 + t;
    if (e < E) atomicAdd(&hist[rows[e] >> 8], 1);
  }
  __syncthreads();
  int v = hist[t];
  if (t < NB) bcnt[t] = v;
  __syncthreads();
  for (int off = 1; off < 512; off <<= 1) {
    int u = (t >= off) ? hist[t - off] : 0;
    __syncthreads();
    hist[t] += u;
    __syncthreads();
  }
  if (t < NB) {
    int ex = hist[t] - v;
    lofs[t] = ex;
    lcur[t] = ex;
    gofs[t] = v ? atomicAdd(&gcursor[t], v) : 0;
  }
  __syncthreads();
#pragma unroll
  for (int i = 0; i < SC_EDGES / 512; ++i) {
    int e = base + i * 512 + t;
    if (e < E) {
      int r = rows[e];
      int b = r >> 8;
      int p = atomicAdd(&lcur[b], 1);
      eds[p] = make_int2(((r & 255) << 17) | cols[e], __float_as_int(vals[e]));
    }
  }
  __syncthreads();
  int wid = t >> 6, lane = t & 63;
  for (int b = wid; b < NB; b += 8) {
    int cnt = bcnt[b];
    int lo = lofs[b];
    int go = gofs[b];
    int lim = (b + 1) << 14;
    for (int j = lane; j < cnt; j += 64)
      if (go + j < lim) packedA[go + j] = eds[lo + j];
  }
}

// ---------------- per-bucket CSR finalize: in-LDS (row, colhalf) sort, coalesced write ----------------

__global__ __launch_bounds__(512) void csr_finalize_kernel(const int* __restrict__ gcursor,
                                                           const int2* __restrict__ packedA,
                                                           int2* __restrict__ packedB,
                                                           int* __restrict__ row_ptr) {
  __shared__ int2 eds[FN_CAPL];    // 72 KB
  __shared__ int pre[512];
  __shared__ int kh[512];
  __shared__ int kofs[512];
  __shared__ int kcur[512];
  int b = blockIdx.x;
  int t = threadIdx.x;
  int cntt = (t < NB) ? (gcursor[t] - t * CAP) : 0;
  pre[t] = cntt;
  __syncthreads();
  for (int off = 1; off < 512; off <<= 1) {
    int u = (t >= off) ? pre[t - off] : 0;
    __syncthreads();
    pre[t] += u;
    __syncthreads();
  }
  int cnt = gcursor[b] - b * CAP;
  int gout = pre[b] - cnt;     // exclusive prefix
  int s0 = b * CAP;
  int end = s0 + cnt;
  kh[t] = 0;
  __syncthreads();
  for (int i = s0 + t; i < end; i += 512) {
    int2 pk = packedA[i];
    int key = ((pk.x >> 17) << 1) | ((pk.x & 0x1FFFF) >= COLHALF);
    atomicAdd(&kh[key], 1);
  }
  __syncthreads();
  int v = kh[t];
  kofs[t] = v;
  __syncthreads();
  for (int off = 1; off < 512; off <<= 1) {
    int u = (t >= off) ? kofs[t - off] : 0;
    __syncthreads();
    kofs[t] += u;
    __syncthreads();
  }
  kcur[t] = kofs[t] - v;     // exclusive per-key offset within bucket
  __syncthreads();
  if (t < RPB) {
    int row = b * RPB + t;
    if (row < N_NODES) row_ptr[row] = gout + kcur[2 * t];
  }
  if (b == 0 && t == 0) row_ptr[N_NODES] = N_EDGES;
  __syncthreads();
  if (cnt <= FN_CAPL) {
    for (int i = s0 + t; i < end; i += 512) {
      int2 pk = packedA[i];
      int key = ((pk.x >> 17) << 1) | ((pk.x & 0x1FFFF) >= COLHALF);
      int p = atomicAdd(&kcur[key], 1);
      eds[p] = pk;
    }
    __syncthreads();
    for (int i = t; i < cnt; i += 512) {
      int2 pk = eds[i];
      packedB[gout + i] = make_int2((pk.x & 0x1FFFF) << 8, pk.y);
    }
  } else {
    for (int i = s0 + t; i < end; i += 512) {
      int2 pk = packedA[i];
      int key = ((pk.x >> 17) << 1) | ((pk.x & 0x1FFFF) >= COLHALF);
      int p = atomicAdd(&kcur[key], 1);
      packedB[gout + p] = make_int2((pk.x & 0x1FFFF) << 8, pk.y);
    }
  }
}

// ---------------- bf16 MFMA GEMM body with register-prefetch double buffer ----------------
// BM = MT*32 tile rows, BN = 128. 256 threads = 4 waves (2x2), MT x 4 frags/wave.
// K-step n+1's global loads are issued right after the barrier, in flight under
// the MFMAs of step n; the next ds_write waits on them via vmcnt.

template <int A_FP32, int OUT_BF16, int K, int N, int MT>
__device__ __forceinline__ void gemm_body(int bx, int by, const void* __restrict__ Aptr,
                                          const __bf16* __restrict__ Bt,
                                          const float* __restrict__ bias,
                                          void* __restrict__ Cptr, int M,
                                          __bf16* __restrict__ As, __bf16* __restrict__ Bs) {
  constexpr int BM = MT * 32;
  int tid = threadIdx.x;
  int lane = tid & 63;
  int w = tid >> 6;
  int wr = w >> 1, wc = w & 1;
  int brow = bx * BM;
  int bcol = by * 128;
  int r16 = lane & 15, kb = lane >> 4;

  f32x4 acc[MT][4];
#pragma unroll
  for (int m = 0; m < MT; ++m)
#pragma unroll
    for (int n = 0; n < 4; ++n) acc[m][n] = (f32x4){0.f, 0.f, 0.f, 0.f};

  float4 pa[MT];            // fp32-A prefetch regs
  bf16x8 pah[MT / 2];       // bf16-A prefetch regs
  bf16x8 pb[2];             // B prefetch regs

  auto loadA = [&](int k0) {
    if (A_FP32) {
      const float* A = (const float*)Aptr;
#pragma unroll
      for (int i = 0; i < MT; ++i) {
        int idx = tid + i * 256;
        int row = idx >> 3;
        int kq = (idx & 7) << 2;
        int gr = brow + row;
        pa[i] = make_float4(0.f, 0.f, 0.f, 0.f);
        if (gr < M) pa[i] = *(const float4*)&A[(size_t)gr * K + k0 + kq];
      }
    } else {
      const __bf16* A = (const __bf16*)Aptr;
#pragma unroll
      for (int i = 0; i < MT / 2; ++i) {
        int idx = tid + i * 256;
        int row = idx >> 2;
        int kq = (idx & 3) << 3;
        int gr = brow + row;
        bf16x8 vv = {};
        if (gr < M) vv = *(const bf16x8*)&A[(size_t)gr * K + k0 + kq];
        pah[i] = vv;
      }
    }
  };
  auto loadB = [&](int k0) {
#pragma unroll
    for (int i = 0; i < 2; ++i) {
      int idx = tid + i * 256;
      int col = idx >> 2;
      int kq = (idx & 3) << 3;
      pb[i] = *(const bf16x8*)&Bt[(size_t)(bcol + col) * K + k0 + kq];
    }
  };
  auto storeAB = [&]() {
    if (A_FP32) {
#pragma unroll
      for (int i = 0; i < MT; ++i) {
        int idx = tid + i * 256;
        int row = idx >> 3;
        int kq = (idx & 7) << 2;
        bf16x4 o;
        o[0] = (__bf16)pa[i].x; o[1] = (__bf16)pa[i].y;
        o[2] = (__bf16)pa[i].z; o[3] = (__bf16)pa[i].w;
        *(bf16x4*)&As[row * 40 + kq] = o;
      }
    } else {
#pragma unroll
      for (int i = 0; i < MT / 2; ++i) {
        int idx = tid + i * 256;
        int row = idx >> 2;
        int kq = (idx & 3) << 3;
        *(bf16x8*)&As[row * 40 + kq] = pah[i];
      }
    }
#pragma unroll
    for (int i = 0; i < 2; ++i) {
      int idx = tid + i * 256;
      int col = idx >> 2;
      int kq = (idx & 3) << 3;
      *(bf16x8*)&Bs[col * 40 + kq] = pb[i];
    }
  };

  loadA(0);
  loadB(0);
  for (int k0 = 0; k0 < K; k0 += 32) {
    storeAB();
    __syncthreads();
    if (k0 + 32 < K) { loadA(k0 + 32); loadB(k0 + 32); }  // in flight under MFMAs
    bf16x8 a[MT], b[4];
#pragma unroll
    for (int m = 0; m < MT; ++m)
      a[m] = *(bf16x8*)&As[(wr * (BM / 2) + m * 16 + r16) * 40 + kb * 8];
#pragma unroll
    for (int n = 0; n < 4; ++n)
      b[n] = *(bf16x8*)&Bs[(wc * 64 + n * 16 + r16) * 40 + kb * 8];
#pragma unroll
    for (int m = 0; m < MT; ++m)
#pragma unroll
      for (int n = 0; n < 4; ++n)
        acc[m][n] = __builtin_amdgcn_mfma_f32_16x16x32_bf16(a[m], b[n], acc[m][n], 0, 0, 0);
    __syncthreads();
  }

  int crow0 = brow + wr * (BM / 2);
  int ccol0 = bcol + wc * 64;
#pragma unroll
  for (int n = 0; n < 4; ++n) {
    int col = ccol0 + n * 16 + r16;
    float bv = bias ? bias[col] : 0.f;
#pragma unroll
    for (int m = 0; m < MT; ++m) {
#pragma unroll
      for (int r = 0; r < 4; ++r) {
        int row = crow0 + m * 16 + kb * 4 + r;
        if (row < M) {
          float val = acc[m][n][r] + bv;
          if (OUT_BF16)
            ((unsigned short*)Cptr)[(size_t)row * N + col] = (unsigned short)bf16_rne(val);
          else
            ((float*)Cptr)[(size_t)row * N + col] = val;
        }
      }
    }
  }
}

// ---------------- standalone GEMM kernel (gemm1: BM=64) ----------------

template <int A_FP32, int OUT_BF16, int K, int N, int MT>
__global__ __launch_bounds__(256) void gemm_mfma_kernel(const void* __restrict__ Aptr,
                                                        const __bf16* __restrict__ Bt,
                                                        const float* __restrict__ bias,
                                                        void* __restrict__ Cptr, int M) {
  __shared__ __align__(16) __bf16 smem[2 * 128 * 40];
  gemm_body<A_FP32, OUT_BF16, K, N, MT>(blockIdx.x, blockIdx.y, Aptr, Bt, bias, Cptr, M,
                                        smem, smem + 128 * 40);
}

// ---------------- CSR SpMM, wave per row, 3-stage software pipeline (round-12) ----------------

#define FMA4(Gv0, Gv1, Gv2, Gv3, Vv0, Vv1, Vv2, Vv3)                                   \
  a0 += Vv0 * bf_lo(Gv0.x); a1 += Vv0 * bf_hi(Gv0.x);                                  \
  a2 += Vv0 * bf_lo(Gv0.y); a3 += Vv0 * bf_hi(Gv0.y);                                  \
  a0 += Vv1 * bf_lo(Gv1.x); a1 += Vv1 * bf_hi(Gv1.x);                                  \
  a2 += Vv1 * bf_lo(Gv1.y); a3 += Vv1 * bf_hi(Gv1.y);                                  \
  a0 += Vv2 * bf_lo(Gv2.x); a1 += Vv2 * bf_hi(Gv2.x);                                  \
  a2 += Vv2 * bf_lo(Gv2.y); a3 += Vv2 * bf_hi(Gv2.y);                                  \
  a0 += Vv3 * bf_lo(Gv3.x); a1 += Vv3 * bf_hi(Gv3.x);                                  \
  a2 += Vv3 * bf_lo(Gv3.y); a3 += Vv3 * bf_hi(Gv3.y);

__global__ __launch_bounds__(256) void spmm_bf16_kernel(const int* __restrict__ row_ptr,
                                                        const int2* __restrict__ packed,
                                                        const uint* __restrict__ src,   // [n][64] dwords
                                                        uint* __restrict__ dst,         // [n][64] dwords
                                                        const float* __restrict__ bias,
                                                        int relu, int nrows) {
  int tid = threadIdx.x;
  int lane = tid & 63;
  int half = lane >> 5;
  int l32 = lane & 31;
  int row = blockIdx.x * 4 + (tid >> 6);
  if (row >= nrows) return;
  int s = row_ptr[row];
  int e = row_ptr[row + 1];
  const char* srcb = (const char*)src + (l32 << 3);
  float a0 = 0.f, a1 = 0.f, a2 = 0.f, a3 = 0.f;
  int i = s;

  if (e - s >= 16) {
    int2 A0 = packed[i + 0 + half], A1 = packed[i + 2 + half];
    int2 A2 = packed[i + 4 + half], A3 = packed[i + 6 + half];
    uint2 G0 = *(const uint2*)(srcb + (uint)A0.x);
    uint2 G1 = *(const uint2*)(srcb + (uint)A1.x);
    uint2 G2 = *(const uint2*)(srcb + (uint)A2.x);
    uint2 G3 = *(const uint2*)(srcb + (uint)A3.x);
    float W0 = __int_as_float(A0.y), W1 = __int_as_float(A1.y);
    float W2 = __int_as_float(A2.y), W3 = __int_as_float(A3.y);
    int2 B0 = packed[i + 8 + half], B1 = packed[i + 10 + half];
    int2 B2 = packed[i + 12 + half], B3 = packed[i + 14 + half];
    i += 16;
    for (; i + 8 <= e; i += 8) {
      uint2 H0 = *(const uint2*)(srcb + (uint)B0.x);
      uint2 H1 = *(const uint2*)(srcb + (uint)B1.x);
      uint2 H2 = *(const uint2*)(srcb + (uint)B2.x);
      uint2 H3 = *(const uint2*)(srcb + (uint)B3.x);
      float X0 = __int_as_float(B0.y), X1 = __int_as_float(B1.y);
      float X2 = __int_as_float(B2.y), X3 = __int_as_float(B3.y);
      B0 = packed[i + 0 + half]; B1 = packed[i + 2 + half];
      B2 = packed[i + 4 + half]; B3 = packed[i + 6 + half];
      FMA4(G0, G1, G2, G3, W0, W1, W2, W3)
      G0 = H0; G1 = H1; G2 = H2; G3 = H3;
      W0 = X0; W1 = X1; W2 = X2; W3 = X3;
    }
    FMA4(G0, G1, G2, G3, W0, W1, W2, W3)
    {
      uint2 H0 = *(const uint2*)(srcb + (uint)B0.x);
      uint2 H1 = *(const uint2*)(srcb + (uint)B1.x);
      uint2 H2 = *(const uint2*)(srcb + (uint)B2.x);
      uint2 H3 = *(const uint2*)(srcb + (uint)B3.x);
      float X0 = __int_as_float(B0.y), X1 = __int_as_float(B1.y);
      float X2 = __int_as_float(B2.y), X3 = __int_as_float(B3.y);
      FMA4(H0, H1, H2, H3, X0, X1, X2, X3)
    }
  }
  for (; i + 8 <= e; i += 8) {
    int2 m0 = packed[i + 0 + half], m1 = packed[i + 2 + half];
    int2 m2 = packed[i + 4 + half], m3 = packed[i + 6 + half];
    uint2 u0 = *(const uint2*)(srcb + (uint)m0.x);
    uint2 u1 = *(const uint2*)(srcb + (uint)m1.x);
    uint2 u2 = *(const uint2*)(srcb + (uint)m2.x);
    uint2 u3 = *(const uint2*)(srcb + (uint)m3.x);
    float v0 = __int_as_float(m0.y), v1 = __int_as_float(m1.y);
    float v2 = __int_as_float(m2.y), v3 = __int_as_float(m3.y);
    FMA4(u0, u1, u2, u3, v0, v1, v2, v3)
  }
  for (; i + 4 <= e; i += 4) {
    int2 m0 = packed[i + 0 + half], m1 = packed[i + 2 + half];
    uint2 u0 = *(const uint2*)(srcb + (uint)m0.x);
    uint2 u1 = *(const uint2*)(srcb + (uint)m1.x);
    float v0 = __int_as_float(m0.y), v1 = __int_as_float(m1.y);
    a0 += v0 * bf_lo(u0.x); a1 += v0 * bf_hi(u0.x); a2 += v0 * bf_lo(u0.y); a3 += v0 * bf_hi(u0.y);
    a0 += v1 * bf_lo(u1.x); a1 += v1 * bf_hi(u1.x); a2 += v1 * bf_lo(u1.y); a3 += v1 * bf_hi(u1.y);
  }
  for (; i < e; i += 2) {
    int ee = i + half;
    int ok = ee < e;
    int2 m = packed[ok ? ee : (e - 1)];
    uint2 u = *(const uint2*)(srcb + (uint)m.x);
    float v = ok ? __int_as_float(m.y) : 0.f;
    a0 += v * bf_lo(u.x); a1 += v * bf_hi(u.x); a2 += v * bf_lo(u.y); a3 += v * bf_hi(u.y);
  }
  a0 += __shfl_xor(a0, 32); a1 += __shfl_xor(a1, 32);
  a2 += __shfl_xor(a2, 32); a3 += __shfl_xor(a3, 32);
  if (half == 0) {
    if (bias) {
      a0 += bias[4 * l32 + 0]; a1 += bias[4 * l32 + 1];
      a2 += bias[4 * l32 + 2]; a3 += bias[4 * l32 + 3];
    }
    if (relu) {
      a0 = fmaxf(a0, 0.f); a1 = fmaxf(a1, 0.f);
      a2 = fmaxf(a2, 0.f); a3 = fmaxf(a3, 0.f);
    }
    uint2 o;
    o.x = bf16_rne(a0) | (bf16_rne(a1) << 16);
    o.y = bf16_rne(a2) | (bf16_rne(a3) << 16);
    *(uint2*)&dst[(size_t)row * 64 + l32 * 2] = o;
  }
}

// ---------------- classifier body ----------------

__device__ __forceinline__ void cls_body(int bid, int clsblks,
                                         const uint* __restrict__ t3,
                                         const float* __restrict__ Wc1,
                                         const float* __restrict__ bc1,
                                         const float* __restrict__ Wc2,
                                         const float* __restrict__ bc2,
                                         float* __restrict__ out1,
                                         float* __restrict__ out2) {
  int half = clsblks >> 1;
  int region = bid >= half;
  int b = region ? bid - half : bid;
  const float* Wc = region ? Wc2 : Wc1;
  const float* bc = region ? bc2 : bc1;
  float* outp = region ? out2 : out1;
  int row0 = region ? TEXT_CNT : 0;
  int nrows = region ? (N_NODES - TEXT_CNT) : TEXT_CNT;

  int lane = threadIdx.x & 63;
  int wav = b * 4 + (threadIdx.x >> 6);
  int nw = half * 4;
  int c = lane & 15;
  int kg = lane >> 4;
  float w[32];
#pragma unroll
  for (int j = 0; j < 32; ++j) w[j] = Wc[(kg * 32 + j) * NCLASS + c];
  float bcv = bc[c];
  for (int r = wav; r < nrows; r += nw) {
    const uint4* rp = (const uint4*)&t3[(size_t)(row0 + r) * 64 + kg * 16];
    float acc = 0.f;
#pragma unroll
    for (int qq = 0; qq < 4; ++qq) {
      uint4 u = rp[qq];
      acc += bf_lo(u.x) * w[qq * 8 + 0] + bf_hi(u.x) * w[qq * 8 + 1]
           + bf_lo(u.y) * w[qq * 8 + 2] + bf_hi(u.y) * w[qq * 8 + 3]
           + bf_lo(u.z) * w[qq * 8 + 4] + bf_hi(u.z) * w[qq * 8 + 5]
           + bf_lo(u.w) * w[qq * 8 + 6] + bf_hi(u.w) * w[qq * 8 + 7];
    }
    acc += __shfl_xor(acc, 16);
    acc += __shfl_xor(acc, 32);
    if (lane < 16) outp[(size_t)r * NCLASS + lane] = acc + bcv;
  }
}

// ---------------- fused: gemm2 (blocks [0,g2blks)) + classifiers ----------------

__global__ __launch_bounds__(256) void fused_g2c_kernel(const uint* __restrict__ t3u,
                                                        const __bf16* __restrict__ W2t,
                                                        const float* __restrict__ b2,
                                                        float* __restrict__ outp,
                                                        const float* __restrict__ Wc1,
                                                        const float* __restrict__ bc1,
                                                        const float* __restrict__ Wc2,
                                                        const float* __restrict__ bc2,
                                                        float* __restrict__ out1,
                                                        float* __restrict__ out2,
                                                        int g2blks, int clsblks) {
  __shared__ __align__(16) __bf16 smem[2 * 128 * 40];
  if ((int)blockIdx.x < g2blks) {
    int bx = blockIdx.x >> 1;
    int by = blockIdx.x & 1;
    gemm_body<0, 0, NHID, NFEAT, 4>(bx, by, t3u, W2t, b2, outp, N_NODES,
                                    smem, smem + 128 * 40);
  } else {
    cls_body(blockIdx.x - g2blks, clsblks, t3u, Wc1, bc1, Wc2, bc2, out1, out2);
  }
}

// ---------------- launch ----------------

extern "C" void kernel_launch(void* const* d_in, const int* in_sizes, int n_in,
                              void* d_out, int out_size, void* d_ws, size_t ws_size,
                              hipStream_t stream) {
  const float* x     = (const float*)d_in[0];
  const int*   arows = (const int*)d_in[1];
  const int*   acols = (const int*)d_in[2];
  const float* avals = (const float*)d_in[3];
  const float* W1    = (const float*)d_in[4];
  const float* b1    = (const float*)d_in[5];
  const float* W2    = (const float*)d_in[6];
  const float* b2    = (const float*)d_in[7];
  const float* cW1   = (const float*)d_in[8];
  const float* cb1   = (const float*)d_in[9];
  const float* cW2   = (const float*)d_in[10];
  const float* cb2   = (const float*)d_in[11];
  float* outp = (float*)d_out;

  char* ws = (char*)d_ws;
  size_t off = 0;
  auto alloc = [&](size_t bytes) -> void* {
    void* p = ws + off;
    off += (bytes + 255) & ~(size_t)255;
    return p;
  };
  uint*  t1u     = (uint*) alloc((size_t)N_NODES * 64 * 4);   // bf16 [N][128]
  uint*  hu      = (uint*) alloc((size_t)N_NODES * 64 * 4);   // bf16 [N][128]
  uint*  t3u     = (uint*) alloc((size_t)N_NODES * 64 * 4);   // bf16 [N][128]
  int2*  packedA = (int2*) alloc((size_t)NB * CAP * 8);       // fixed-cap buckets
  int2*  packedB = (int2*) alloc((size_t)N_EDGES * 8);        // row-grouped (CSR)
  int*   gcursor = (int*)  alloc((size_t)NB * 4);
  int*   rowp    = (int*)  alloc((size_t)(N_NODES + 1) * 4);
  unsigned short* W1t = (unsigned short*)alloc((size_t)NHID * NFEAT * 2);  // [128][256]
  unsigned short* W2t = (unsigned short*)alloc((size_t)NFEAT * NHID * 2);  // [256][128]
  float* Wc1     = (float*)alloc(NHID * NCLASS * 4);
  float* Wc2     = (float*)alloc(NHID * NCLASS * 4);
  float* bc1     = (float*)alloc(64);
  float* bc2     = (float*)alloc(64);

  // ---- 1. fused prep (weights + cursors) ----
  prep_kernel<<<(69632 + NB + 255) / 256, 256, 0, stream>>>(
      W1, W2, b2, cW1, cb1, cW2, cb2, W1t, W2t, Wc1, bc1, Wc2, bc2, gcursor);

  // ---- 2. scatter with in-LDS counting sort ----
  scatter_sort_kernel<<<SC_BLKS, 512, 0, stream>>>(arows, acols, avals, gcursor, packedA, N_EDGES);

  // ---- 3. finalize: in-LDS (row,colhalf) sort, coalesced CSR write ----
  csr_finalize_kernel<<<NB, 512, 0, stream>>>(gcursor, packedA, packedB, rowp);

  // ---- 4. t1 = bf16(x @ W1), BM=64 (1563 blocks) + register prefetch ----
  int mblk64 = (N_NODES + 63) / 64;   // 1563
  gemm_mfma_kernel<1, 1, NFEAT, NHID, 2><<<dim3(mblk64, 1), 256, 0, stream>>>(
      x, (const __bf16*)W1t, nullptr, t1u, N_NODES);

  // ---- 5. h = bf16(relu(A @ t1 + b1)) ----
  int sblk = (N_NODES + 3) / 4;
  spmm_bf16_kernel<<<sblk, 256, 0, stream>>>(rowp, packedB, t1u, hu, b1, 1, N_NODES);
  // ---- 6. t3 = bf16(A @ h) ----
  spmm_bf16_kernel<<<sblk, 256, 0, stream>>>(rowp, packedB, hu, t3u, nullptr, 0, N_NODES);

  // ---- 7. fused: out = t3 @ W2 + b2 (fp32) + classifiers ----
  int mblk = (N_NODES + 127) / 128;  // 782
  int g2blks = mblk * 2;             // 1564
  int clsblks = 2048;
  fused_g2c_kernel<<<g2blks + clsblks, 256, 0, stream>>>(
      t3u, (const __bf16*)W2t, b2, outp, Wc1, bc1, Wc2, bc2,
      outp + (size_t)N_NODES * NFEAT,
      outp + (size_t)N_NODES * NFEAT + (size_t)TEXT_CNT * NCLASS,
      g2blks, clsblks);
}

// Round 15
// 394.399 us; speedup vs baseline: 1.1408x; 1.0254x over previous
//
#include <hip/hip_runtime.h>

#define N_NODES  100000
#define N_EDGES  3200000
#define NFEAT    256
#define NHID     128
#define NCLASS   16
#define TEXT_CNT 50000

#define RPB      256                          // rows per bucket
#define NB       ((N_NODES + RPB - 1) / RPB)  // 391 buckets
#define CAP      16384                        // fixed bucket capacity (2^14)
#define SC_EDGES 4096                         // edges per scatter block
#define SC_BLKS  ((N_EDGES + SC_EDGES - 1) / SC_EDGES)  // 782
#define FN_CAPL  9216                         // finalize LDS edge capacity (mean+11sigma)
#define COLHALF  (N_NODES / 2)
// fused kernel LDS: scatter 32768(eds)+2048(hist)+4*NB*4(ctrl)=41072 >= gemm 2*15360
#define FUS_LDS  41072

typedef unsigned int uint;
typedef __bf16 bf16x8 __attribute__((ext_vector_type(8)));
typedef __bf16 bf16x4 __attribute__((ext_vector_type(4)));
typedef float f32x4 __attribute__((ext_vector_type(4)));

__device__ inline uint bf16_rne(float f) {
  uint u = __float_as_uint(f);
  return (u + 0x7fffu + ((u >> 16) & 1u)) >> 16;
}
__device__ inline float bf_lo(uint u) { return __uint_as_float(u << 16); }
__device__ inline float bf_hi(uint u) { return __uint_as_float(u & 0xffff0000u); }

// ---------------- fused prep: W1t, W2t, Wc1/2, bc1/2, cursor init ----------------

__global__ __launch_bounds__(256) void prep_kernel(const float* __restrict__ W1,
                                                   const float* __restrict__ W2,
                                                   const float* __restrict__ b2,
                                                   const float* __restrict__ cW1,
                                                   const float* __restrict__ cb1,
                                                   const float* __restrict__ cW2,
                                                   const float* __restrict__ cb2,
                                                   unsigned short* __restrict__ W1t,
                                                   unsigned short* __restrict__ W2t,
                                                   float* __restrict__ Wc1, float* __restrict__ bc1,
                                                   float* __restrict__ Wc2, float* __restrict__ bc2,
                                                   int* __restrict__ gcursor) {
  int idx = blockIdx.x * 256 + threadIdx.x;
  if (idx < 32768) {                       // W1t[n][k] = bf16(W1[k][n]), K=256,N=128
    int n = idx >> 8, k = idx & 255;
    W1t[idx] = (unsigned short)bf16_rne(W1[(size_t)k * NHID + n]);
  } else if (idx < 65536) {                // W2t[n][k] = bf16(W2[k][n]), K=128,N=256
    int i2 = idx - 32768;
    int n = i2 >> 7, k = i2 & 127;
    W2t[i2] = (unsigned short)bf16_rne(W2[(size_t)k * NFEAT + n]);
  } else if (idx < 69632) {                // Wc = W2 @ cW
    int e = idx - 65536;
    int set = e >> 11;
    int e2 = e & 2047;
    int i = e2 >> 4, c = e2 & 15;
    const float* cw = set ? cW2 : cW1;
    float acc = 0.f;
    for (int k = 0; k < NFEAT; ++k)
      acc += W2[(size_t)i * NFEAT + k] * cw[k * NCLASS + c];
    (set ? Wc2 : Wc1)[e2] = acc;
    if (e < 32) {
      int s2 = e >> 4, c2 = e & 15;
      const float* cwb = s2 ? cW2 : cW1;
      float b = (s2 ? cb2 : cb1)[c2];
      for (int k = 0; k < NFEAT; ++k) b += b2[k] * cwb[k * NCLASS + c2];
      (s2 ? bc2 : bc1)[c2] = b;
    }
  } else if (idx < 69632 + NB) {           // gcursor[b] = b*CAP
    int b = idx - 69632;
    gcursor[b] = b * CAP;
  }
}

// ---------------- scatter body (512 threads, 41072 B of dynamic LDS) ----------------
// packedA[p] = { (rowlocal<<17) | col , float_bits(val) }

__device__ __forceinline__ void scatter_body(int bx, const int* __restrict__ rows,
                                             const int* __restrict__ cols,
                                             const float* __restrict__ vals,
                                             int* __restrict__ gcursor,
                                             int2* __restrict__ packedA, int E,
                                             char* __restrict__ dynbuf) {
  int2* eds = (int2*)dynbuf;                  // 4096 * 8
  int* hist = (int*)(dynbuf + 32768);         // 512
  int* bcnt = hist + 512;                     // NB
  int* lofs = bcnt + NB;
  int* lcur = lofs + NB;
  int* gofs = lcur + NB;
  int t = threadIdx.x;
  int base = bx * SC_EDGES;
  hist[t] = 0;
  __syncthreads();
#pragma unroll
  for (int i = 0; i < SC_EDGES / 512; ++i) {
    int e = base + i * 512 + t;
    if (e < E) atomicAdd(&hist[rows[e] >> 8], 1);
  }
  __syncthreads();
  int v = hist[t];
  if (t < NB) bcnt[t] = v;
  __syncthreads();
  for (int off = 1; off < 512; off <<= 1) {
    int u = (t >= off) ? hist[t - off] : 0;
    __syncthreads();
    hist[t] += u;
    __syncthreads();
  }
  if (t < NB) {
    int ex = hist[t] - v;
    lofs[t] = ex;
    lcur[t] = ex;
    gofs[t] = v ? atomicAdd(&gcursor[t], v) : 0;
  }
  __syncthreads();
#pragma unroll
  for (int i = 0; i < SC_EDGES / 512; ++i) {
    int e = base + i * 512 + t;
    if (e < E) {
      int r = rows[e];
      int b = r >> 8;
      int p = atomicAdd(&lcur[b], 1);
      eds[p] = make_int2(((r & 255) << 17) | cols[e], __float_as_int(vals[e]));
    }
  }
  __syncthreads();
  int wid = t >> 6, lane = t & 63;
  for (int b = wid; b < NB; b += 8) {
    int cnt = bcnt[b];
    int lo = lofs[b];
    int go = gofs[b];
    int lim = (b + 1) << 14;
    for (int j = lane; j < cnt; j += 64)
      if (go + j < lim) packedA[go + j] = eds[lo + j];
  }
}

// ---------------- bf16 MFMA GEMM body, register-prefetch double buffer ----------------
// BM = MT*32, BN = 128, 256 threads (tid passed in) = 4 waves (2x2), MT x 4 frags.

template <int A_FP32, int OUT_BF16, int K, int N, int MT>
__device__ __forceinline__ void gemm_body(int bx, int by, const void* __restrict__ Aptr,
                                          const __bf16* __restrict__ Bt,
                                          const float* __restrict__ bias,
                                          void* __restrict__ Cptr, int M, int tid,
                                          __bf16* __restrict__ As, __bf16* __restrict__ Bs) {
  constexpr int BM = MT * 32;
  int lane = tid & 63;
  int w = tid >> 6;
  int wr = w >> 1, wc = w & 1;
  int brow = bx * BM;
  int bcol = by * 128;
  int r16 = lane & 15, kb = lane >> 4;

  f32x4 acc[MT][4];
#pragma unroll
  for (int m = 0; m < MT; ++m)
#pragma unroll
    for (int n = 0; n < 4; ++n) acc[m][n] = (f32x4){0.f, 0.f, 0.f, 0.f};

  float4 pa[MT];
  bf16x8 pah[MT / 2];
  bf16x8 pb[2];

  auto loadA = [&](int k0) {
    if (A_FP32) {
      const float* A = (const float*)Aptr;
#pragma unroll
      for (int i = 0; i < MT; ++i) {
        int idx = tid + i * 256;
        int row = idx >> 3;
        int kq = (idx & 7) << 2;
        int gr = brow + row;
        pa[i] = make_float4(0.f, 0.f, 0.f, 0.f);
        if (gr < M) pa[i] = *(const float4*)&((const float*)Aptr)[(size_t)gr * K + k0 + kq];
        (void)A;
      }
    } else {
      const __bf16* A = (const __bf16*)Aptr;
#pragma unroll
      for (int i = 0; i < MT / 2; ++i) {
        int idx = tid + i * 256;
        int row = idx >> 2;
        int kq = (idx & 3) << 3;
        int gr = brow + row;
        bf16x8 vv = {};
        if (gr < M) vv = *(const bf16x8*)&A[(size_t)gr * K + k0 + kq];
        pah[i] = vv;
      }
    }
  };
  auto loadB = [&](int k0) {
#pragma unroll
    for (int i = 0; i < 2; ++i) {
      int idx = tid + i * 256;
      int col = idx >> 2;
      int kq = (idx & 3) << 3;
      pb[i] = *(const bf16x8*)&Bt[(size_t)(bcol + col) * K + k0 + kq];
    }
  };
  auto storeAB = [&]() {
    if (A_FP32) {
#pragma unroll
      for (int i = 0; i < MT; ++i) {
        int idx = tid + i * 256;
        int row = idx >> 3;
        int kq = (idx & 7) << 2;
        bf16x4 o;
        o[0] = (__bf16)pa[i].x; o[1] = (__bf16)pa[i].y;
        o[2] = (__bf16)pa[i].z; o[3] = (__bf16)pa[i].w;
        *(bf16x4*)&As[row * 40 + kq] = o;
      }
    } else {
#pragma unroll
      for (int i = 0; i < MT / 2; ++i) {
        int idx = tid + i * 256;
        int row = idx >> 2;
        int kq = (idx & 3) << 3;
        *(bf16x8*)&As[row * 40 + kq] = pah[i];
      }
    }
#pragma unroll
    for (int i = 0; i < 2; ++i) {
      int idx = tid + i * 256;
      int col = idx >> 2;
      int kq = (idx & 3) << 3;
      *(bf16x8*)&Bs[col * 40 + kq] = pb[i];
    }
  };

  loadA(0);
  loadB(0);
  for (int k0 = 0; k0 < K; k0 += 32) {
    storeAB();
    __syncthreads();
    if (k0 + 32 < K) { loadA(k0 + 32); loadB(k0 + 32); }
    bf16x8 a[MT], b[4];
#pragma unroll
    for (int m = 0; m < MT; ++m)
      a[m] = *(bf16x8*)&As[(wr * (BM / 2) + m * 16 + r16) * 40 + kb * 8];
#pragma unroll
    for (int n = 0; n < 4; ++n)
      b[n] = *(bf16x8*)&Bs[(wc * 64 + n * 16 + r16) * 40 + kb * 8];
#pragma unroll
    for (int m = 0; m < MT; ++m)
#pragma unroll
      for (int n = 0; n < 4; ++n)
        acc[m][n] = __builtin_amdgcn_mfma_f32_16x16x32_bf16(a[m], b[n], acc[m][n], 0, 0, 0);
    __syncthreads();
  }

  int crow0 = brow + wr * (BM / 2);
  int ccol0 = bcol + wc * 64;
#pragma unroll
  for (int n = 0; n < 4; ++n) {
    int col = ccol0 + n * 16 + r16;
    float bv = bias ? bias[col] : 0.f;
#pragma unroll
    for (int m = 0; m < MT; ++m) {
#pragma unroll
      for (int r = 0; r < 4; ++r) {
        int row = crow0 + m * 16 + kb * 4 + r;
        if (row < M) {
          float val = acc[m][n][r] + bv;
          if (OUT_BF16)
            ((unsigned short*)Cptr)[(size_t)row * N + col] = (unsigned short)bf16_rne(val);
          else
            ((float*)Cptr)[(size_t)row * N + col] = val;
        }
      }
    }
  }
}

// ---------------- fused: scatter (blocks [0,SC_BLKS)) + gemm1 pairs (rest) ----------------
// gemm pairs: 512-thread block = two independent 256-thread BM=64 tiles (identical
// barrier schedule in both halves -> block-level __syncthreads is safe).

__global__ __launch_bounds__(512) void fused_sg1_kernel(
    const int* __restrict__ rows, const int* __restrict__ cols, const float* __restrict__ vals,
    int* __restrict__ gcursor, int2* __restrict__ packedA, int E,
    const float* __restrict__ x, const __bf16* __restrict__ W1t, uint* __restrict__ t1u,
    int M, int mblk64) {
  extern __shared__ __align__(16) char dynbuf[];
  if ((int)blockIdx.x < SC_BLKS) {
    scatter_body(blockIdx.x, rows, cols, vals, gcursor, packedA, E, dynbuf);
  } else {
    int p = blockIdx.x - SC_BLKS;
    int sub = threadIdx.x >> 8;          // 0 or 1
    int tile = p * 2 + sub;              // may be == mblk64 (padded; fully guarded)
    int tidl = threadIdx.x & 255;
    __bf16* As = (__bf16*)(dynbuf + sub * 15360);
    __bf16* Bs = As + 64 * 40;
    gemm_body<1, 1, NFEAT, NHID, 2>(tile, 0, x, W1t, nullptr, t1u, M, tidl, As, Bs);
  }
}

// ---------------- per-bucket CSR finalize: in-LDS (row, colhalf) sort, coalesced write ----------------

__global__ __launch_bounds__(512) void csr_finalize_kernel(const int* __restrict__ gcursor,
                                                           const int2* __restrict__ packedA,
                                                           int2* __restrict__ packedB,
                                                           int* __restrict__ row_ptr) {
  __shared__ int2 eds[FN_CAPL];    // 72 KB
  __shared__ int pre[512];
  __shared__ int kh[512];
  __shared__ int kofs[512];
  __shared__ int kcur[512];
  int b = blockIdx.x;
  int t = threadIdx.x;
  int cntt = (t < NB) ? (gcursor[t] - t * CAP) : 0;
  pre[t] = cntt;
  __syncthreads();
  for (int off = 1; off < 512; off <<= 1) {
    int u = (t >= off) ? pre[t - off] : 0;
    __syncthreads();
    pre[t] += u;
    __syncthreads();
  }
  int cnt = gcursor[b] - b * CAP;
  int gout = pre[b] - cnt;     // exclusive prefix
  int s0 = b * CAP;
  int end = s0 + cnt;
  kh[t] = 0;
  __syncthreads();
  for (int i = s0 + t; i < end; i += 512) {
    int2 pk = packedA[i];
    int key = ((pk.x >> 17) << 1) | ((pk.x & 0x1FFFF) >= COLHALF);
    atomicAdd(&kh[key], 1);
  }
  __syncthreads();
  int v = kh[t];
  kofs[t] = v;
  __syncthreads();
  for (int off = 1; off < 512; off <<= 1) {
    int u = (t >= off) ? kofs[t - off] : 0;
    __syncthreads();
    kofs[t] += u;
    __syncthreads();
  }
  kcur[t] = kofs[t] - v;
  __syncthreads();
  if (t < RPB) {
    int row = b * RPB + t;
    if (row < N_NODES) row_ptr[row] = gout + kcur[2 * t];
  }
  if (b == 0 && t == 0) row_ptr[N_NODES] = N_EDGES;
  __syncthreads();
  if (cnt <= FN_CAPL) {
    for (int i = s0 + t; i < end; i += 512) {
      int2 pk = packedA[i];
      int key = ((pk.x >> 17) << 1) | ((pk.x & 0x1FFFF) >= COLHALF);
      int p = atomicAdd(&kcur[key], 1);
      eds[p] = pk;
    }
    __syncthreads();
    for (int i = t; i < cnt; i += 512) {
      int2 pk = eds[i];
      packedB[gout + i] = make_int2((pk.x & 0x1FFFF) << 8, pk.y);
    }
  } else {
    for (int i = s0 + t; i < end; i += 512) {
      int2 pk = packedA[i];
      int key = ((pk.x >> 17) << 1) | ((pk.x & 0x1FFFF) >= COLHALF);
      int p = atomicAdd(&kcur[key], 1);
      packedB[gout + p] = make_int2((pk.x & 0x1FFFF) << 8, pk.y);
    }
  }
}

// ---------------- CSR SpMM, wave per row, 3-stage software pipeline ----------------

#define FMA4(Gv0, Gv1, Gv2, Gv3, Vv0, Vv1, Vv2, Vv3)                                   \
  a0 += Vv0 * bf_lo(Gv0.x); a1 += Vv0 * bf_hi(Gv0.x);                                  \
  a2 += Vv0 * bf_lo(Gv0.y); a3 += Vv0 * bf_hi(Gv0.y);                                  \
  a0 += Vv1 * bf_lo(Gv1.x); a1 += Vv1 * bf_hi(Gv1.x);                                  \
  a2 += Vv1 * bf_lo(Gv1.y); a3 += Vv1 * bf_hi(Gv1.y);                                  \
  a0 += Vv2 * bf_lo(Gv2.x); a1 += Vv2 * bf_hi(Gv2.x);                                  \
  a2 += Vv2 * bf_lo(Gv2.y); a3 += Vv2 * bf_hi(Gv2.y);                                  \
  a0 += Vv3 * bf_lo(Gv3.x); a1 += Vv3 * bf_hi(Gv3.x);                                  \
  a2 += Vv3 * bf_lo(Gv3.y); a3 += Vv3 * bf_hi(Gv3.y);

__global__ __launch_bounds__(256) void spmm_bf16_kernel(const int* __restrict__ row_ptr,
                                                        const int2* __restrict__ packed,
                                                        const uint* __restrict__ src,   // [n][64] dwords
                                                        uint* __restrict__ dst,         // [n][64] dwords
                                                        const float* __restrict__ bias,
                                                        int relu, int nrows) {
  int tid = threadIdx.x;
  int lane = tid & 63;
  int half = lane >> 5;
  int l32 = lane & 31;
  int row = blockIdx.x * 4 + (tid >> 6);
  if (row >= nrows) return;
  int s = row_ptr[row];
  int e = row_ptr[row + 1];
  const char* srcb = (const char*)src + (l32 << 3);
  float a0 = 0.f, a1 = 0.f, a2 = 0.f, a3 = 0.f;
  int i = s;

  if (e - s >= 16) {
    int2 A0 = packed[i + 0 + half], A1 = packed[i + 2 + half];
    int2 A2 = packed[i + 4 + half], A3 = packed[i + 6 + half];
    uint2 G0 = *(const uint2*)(srcb + (uint)A0.x);
    uint2 G1 = *(const uint2*)(srcb + (uint)A1.x);
    uint2 G2 = *(const uint2*)(srcb + (uint)A2.x);
    uint2 G3 = *(const uint2*)(srcb + (uint)A3.x);
    float W0 = __int_as_float(A0.y), W1 = __int_as_float(A1.y);
    float W2 = __int_as_float(A2.y), W3 = __int_as_float(A3.y);
    int2 B0 = packed[i + 8 + half], B1 = packed[i + 10 + half];
    int2 B2 = packed[i + 12 + half], B3 = packed[i + 14 + half];
    i += 16;
    for (; i + 8 <= e; i += 8) {
      uint2 H0 = *(const uint2*)(srcb + (uint)B0.x);
      uint2 H1 = *(const uint2*)(srcb + (uint)B1.x);
      uint2 H2 = *(const uint2*)(srcb + (uint)B2.x);
      uint2 H3 = *(const uint2*)(srcb + (uint)B3.x);
      float X0 = __int_as_float(B0.y), X1 = __int_as_float(B1.y);
      float X2 = __int_as_float(B2.y), X3 = __int_as_float(B3.y);
      B0 = packed[i + 0 + half]; B1 = packed[i + 2 + half];
      B2 = packed[i + 4 + half]; B3 = packed[i + 6 + half];
      FMA4(G0, G1, G2, G3, W0, W1, W2, W3)
      G0 = H0; G1 = H1; G2 = H2; G3 = H3;
      W0 = X0; W1 = X1; W2 = X2; W3 = X3;
    }
    FMA4(G0, G1, G2, G3, W0, W1, W2, W3)
    {
      uint2 H0 = *(const uint2*)(srcb + (uint)B0.x);
      uint2 H1 = *(const uint2*)(srcb + (uint)B1.x);
      uint2 H2 = *(const uint2*)(srcb + (uint)B2.x);
      uint2 H3 = *(const uint2*)(srcb + (uint)B3.x);
      float X0 = __int_as_float(B0.y), X1 = __int_as_float(B1.y);
      float X2 = __int_as_float(B2.y), X3 = __int_as_float(B3.y);
      FMA4(H0, H1, H2, H3, X0, X1, X2, X3)
    }
  }
  for (; i + 8 <= e; i += 8) {
    int2 m0 = packed[i + 0 + half], m1 = packed[i + 2 + half];
    int2 m2 = packed[i + 4 + half], m3 = packed[i + 6 + half];
    uint2 u0 = *(const uint2*)(srcb + (uint)m0.x);
    uint2 u1 = *(const uint2*)(srcb + (uint)m1.x);
    uint2 u2 = *(const uint2*)(srcb + (uint)m2.x);
    uint2 u3 = *(const uint2*)(srcb + (uint)m3.x);
    float v0 = __int_as_float(m0.y), v1 = __int_as_float(m1.y);
    float v2 = __int_as_float(m2.y), v3 = __int_as_float(m3.y);
    FMA4(u0, u1, u2, u3, v0, v1, v2, v3)
  }
  for (; i + 4 <= e; i += 4) {
    int2 m0 = packed[i + 0 + half], m1 = packed[i + 2 + half];
    uint2 u0 = *(const uint2*)(srcb + (uint)m0.x);
    uint2 u1 = *(const uint2*)(srcb + (uint)m1.x);
    float v0 = __int_as_float(m0.y), v1 = __int_as_float(m1.y);
    a0 += v0 * bf_lo(u0.x); a1 += v0 * bf_hi(u0.x); a2 += v0 * bf_lo(u0.y); a3 += v0 * bf_hi(u0.y);
    a0 += v1 * bf_lo(u1.x); a1 += v1 * bf_hi(u1.x); a2 += v1 * bf_lo(u1.y); a3 += v1 * bf_hi(u1.y);
  }
  for (; i < e; i += 2) {
    int ee = i + half;
    int ok = ee < e;
    int2 m = packed[ok ? ee : (e - 1)];
    uint2 u = *(const uint2*)(srcb + (uint)m.x);
    float v = ok ? __int_as_float(m.y) : 0.f;
    a0 += v * bf_lo(u.x); a1 += v * bf_hi(u.x); a2 += v * bf_lo(u.y); a3 += v * bf_hi(u.y);
  }
  a0 += __shfl_xor(a0, 32); a1 += __shfl_xor(a1, 32);
  a2 += __shfl_xor(a2, 32); a3 += __shfl_xor(a3, 32);
  if (half == 0) {
    if (bias) {
      a0 += bias[4 * l32 + 0]; a1 += bias[4 * l32 + 1];
      a2 += bias[4 * l32 + 2]; a3 += bias[4 * l32 + 3];
    }
    if (relu) {
      a0 = fmaxf(a0, 0.f); a1 = fmaxf(a1, 0.f);
      a2 = fmaxf(a2, 0.f); a3 = fmaxf(a3, 0.f);
    }
    uint2 o;
    o.x = bf16_rne(a0) | (bf16_rne(a1) << 16);
    o.y = bf16_rne(a2) | (bf16_rne(a3) << 16);
    *(uint2*)&dst[(size_t)row * 64 + l32 * 2] = o;
  }
}

// ---------------- classifier body ----------------

__device__ __forceinline__ void cls_body(int bid, int clsblks,
                                         const uint* __restrict__ t3,
                                         const float* __restrict__ Wc1,
                                         const float* __restrict__ bc1,
                                         const float* __restrict__ Wc2,
                                         const float* __restrict__ bc2,
                                         float* __restrict__ out1,
                                         float* __restrict__ out2) {
  int half = clsblks >> 1;
  int region = bid >= half;
  int b = region ? bid - half : bid;
  const float* Wc = region ? Wc2 : Wc1;
  const float* bc = region ? bc2 : bc1;
  float* outp = region ? out2 : out1;
  int row0 = region ? TEXT_CNT : 0;
  int nrows = region ? (N_NODES - TEXT_CNT) : TEXT_CNT;

  int lane = threadIdx.x & 63;
  int wav = b * 4 + (threadIdx.x >> 6);
  int nw = half * 4;
  int c = lane & 15;
  int kg = lane >> 4;
  float w[32];
#pragma unroll
  for (int j = 0; j < 32; ++j) w[j] = Wc[(kg * 32 + j) * NCLASS + c];
  float bcv = bc[c];
  for (int r = wav; r < nrows; r += nw) {
    const uint4* rp = (const uint4*)&t3[(size_t)(row0 + r) * 64 + kg * 16];
    float acc = 0.f;
#pragma unroll
    for (int qq = 0; qq < 4; ++qq) {
      uint4 u = rp[qq];
      acc += bf_lo(u.x) * w[qq * 8 + 0] + bf_hi(u.x) * w[qq * 8 + 1]
           + bf_lo(u.y) * w[qq * 8 + 2] + bf_hi(u.y) * w[qq * 8 + 3]
           + bf_lo(u.z) * w[qq * 8 + 4] + bf_hi(u.z) * w[qq * 8 + 5]
           + bf_lo(u.w) * w[qq * 8 + 6] + bf_hi(u.w) * w[qq * 8 + 7];
    }
    acc += __shfl_xor(acc, 16);
    acc += __shfl_xor(acc, 32);
    if (lane < 16) outp[(size_t)r * NCLASS + lane] = acc + bcv;
  }
}

// ---------------- fused: gemm2 BM=64 (blocks [0,g2blks)) + classifiers ----------------

__global__ __launch_bounds__(256) void fused_g2c_kernel(const uint* __restrict__ t3u,
                                                        const __bf16* __restrict__ W2t,
                                                        const float* __restrict__ b2,
                                                        float* __restrict__ outp,
                                                        const float* __restrict__ Wc1,
                                                        const float* __restrict__ bc1,
                                                        const float* __restrict__ Wc2,
                                                        const float* __restrict__ bc2,
                                                        float* __restrict__ out1,
                                                        float* __restrict__ out2,
                                                        int g2blks, int clsblks) {
  __shared__ __align__(16) __bf16 smem[64 * 40 + 128 * 40];
  if ((int)blockIdx.x < g2blks) {
    int bx = blockIdx.x >> 1;
    int by = blockIdx.x & 1;
    gemm_body<0, 0, NHID, NFEAT, 2>(bx, by, t3u, W2t, b2, outp, N_NODES, threadIdx.x,
                                    smem, smem + 64 * 40);
  } else {
    cls_body(blockIdx.x - g2blks, clsblks, t3u, Wc1, bc1, Wc2, bc2, out1, out2);
  }
}

// ---------------- launch ----------------

extern "C" void kernel_launch(void* const* d_in, const int* in_sizes, int n_in,
                              void* d_out, int out_size, void* d_ws, size_t ws_size,
                              hipStream_t stream) {
  const float* x     = (const float*)d_in[0];
  const int*   arows = (const int*)d_in[1];
  const int*   acols = (const int*)d_in[2];
  const float* avals = (const float*)d_in[3];
  const float* W1    = (const float*)d_in[4];
  const float* b1    = (const float*)d_in[5];
  const float* W2    = (const float*)d_in[6];
  const float* b2    = (const float*)d_in[7];
  const float* cW1   = (const float*)d_in[8];
  const float* cb1   = (const float*)d_in[9];
  const float* cW2   = (const float*)d_in[10];
  const float* cb2   = (const float*)d_in[11];
  float* outp = (float*)d_out;

  char* ws = (char*)d_ws;
  size_t off = 0;
  auto alloc = [&](size_t bytes) -> void* {
    void* p = ws + off;
    off += (bytes + 255) & ~(size_t)255;
    return p;
  };
  uint*  t1u     = (uint*) alloc((size_t)N_NODES * 64 * 4);   // bf16 [N][128]
  uint*  hu      = (uint*) alloc((size_t)N_NODES * 64 * 4);   // bf16 [N][128]
  uint*  t3u     = (uint*) alloc((size_t)N_NODES * 64 * 4);   // bf16 [N][128]
  int2*  packedA = (int2*) alloc((size_t)NB * CAP * 8);       // fixed-cap buckets
  int2*  packedB = (int2*) alloc((size_t)N_EDGES * 8);        // row-grouped (CSR)
  int*   gcursor = (int*)  alloc((size_t)NB * 4);
  int*   rowp    = (int*)  alloc((size_t)(N_NODES + 1) * 4);
  unsigned short* W1t = (unsigned short*)alloc((size_t)NHID * NFEAT * 2);  // [128][256]
  unsigned short* W2t = (unsigned short*)alloc((size_t)NFEAT * NHID * 2);  // [256][128]
  float* Wc1     = (float*)alloc(NHID * NCLASS * 4);
  float* Wc2     = (float*)alloc(NHID * NCLASS * 4);
  float* bc1     = (float*)alloc(64);
  float* bc2     = (float*)alloc(64);

  // ---- 1. fused prep (weights + cursors) ----
  prep_kernel<<<(69632 + NB + 255) / 256, 256, 0, stream>>>(
      W1, W2, b2, cW1, cb1, cW2, cb2, W1t, W2t, Wc1, bc1, Wc2, bc2, gcursor);

  // ---- 2. fused: scatter (sorted runs) + t1 = bf16(x @ W1) BM=64 pairs ----
  int mblk64 = (N_NODES + 63) / 64;    // 1563
  int gpairs = (mblk64 + 1) / 2;       // 782 (last pair has one guarded dummy tile)
  fused_sg1_kernel<<<SC_BLKS + gpairs, 512, FUS_LDS, stream>>>(
      arows, acols, avals, gcursor, packedA, N_EDGES,
      x, (const __bf16*)W1t, t1u, N_NODES, mblk64);

  // ---- 3. finalize: in-LDS (row,colhalf) sort, coalesced CSR write ----
  csr_finalize_kernel<<<NB, 512, 0, stream>>>(gcursor, packedA, packedB, rowp);

  // ---- 4. h = bf16(relu(A @ t1 + b1)) ----
  int sblk = (N_NODES + 3) / 4;
  spmm_bf16_kernel<<<sblk, 256, 0, stream>>>(rowp, packedB, t1u, hu, b1, 1, N_NODES);
  // ---- 5. t3 = bf16(A @ h) ----
  spmm_bf16_kernel<<<sblk, 256, 0, stream>>>(rowp, packedB, hu, t3u, nullptr, 0, N_NODES);

  // ---- 6. fused: out = t3 @ W2 + b2 (fp32, BM=64) + classifiers ----
  int g2blks = mblk64 * 2;   // 3126
  int clsblks = 2048;
  fused_g2c_kernel<<<g2blks + clsblks, 256, 0, stream>>>(
      t3u, (const __bf16*)W2t, b2, outp, Wc1, bc1, Wc2, bc2,
      outp + (size_t)N_NODES * NFEAT,
      outp + (size_t)N_NODES * NFEAT + (size_t)TEXT_CNT * NCLASS,
      g2blks, clsblks);
}